// Round 7
// baseline (316.965 us; speedup 1.0000x reference)
//
#include <hip/hip_runtime.h>

#define NN 50000
#define NE 800000
#define D 128

#define CH 64              // edge chunks
#define EPC (NE / CH)      // 12500 edges per chunk
#define RG 8               // node ranges
#define NPR (NN / RG)      // 6250 nodes per range

typedef short bf16x8 __attribute__((ext_vector_type(8)));
typedef float f32x4 __attribute__((ext_vector_type(4)));

// ---------------- bf16 helpers ----------------

__device__ __forceinline__ unsigned bf16rne(float f) {
  unsigned u = __float_as_uint(f);
  return (u + 0x7fffu + ((u >> 16) & 1u)) >> 16;
}
__device__ __forceinline__ unsigned packbf(float lo, float hi) {
  return bf16rne(lo) | (bf16rne(hi) << 16);
}

// fused: x->bf16 (blocks 0..6249), W^T bf16 x3 (blocks 6250..6441),
// zero row NN of BOTH gather tables (block 6442).
__global__ __launch_bounds__(256) void cvtw_kernel(const float* __restrict__ x,
                                                   const float* __restrict__ W1,
                                                   const float* __restrict__ W2,
                                                   const float* __restrict__ W3,
                                                   unsigned short* __restrict__ hbf,
                                                   unsigned short* __restrict__ tbl2,
                                                   unsigned short* __restrict__ T1,
                                                   unsigned short* __restrict__ T2,
                                                   unsigned short* __restrict__ T3) {
  int b = blockIdx.x;
  int tid = threadIdx.x;
  if (b < 6250) {
    int i = b * 256 + tid;  // NN*D/4 = 1.6M exactly
    float4 v = ((const float4*)x)[i];
    uint2 p;
    p.x = packbf(v.x, v.y);
    p.y = packbf(v.z, v.w);
    ((uint2*)hbf)[i] = p;
  } else if (b < 6442) {
    int g = b - 6250;
    int w = g >> 6;
    int i = (g & 63) * 256 + tid;  // 0..16383
    const float* W = (w == 0) ? W1 : (w == 1) ? W2 : W3;
    unsigned short* T = (w == 0) ? T1 : (w == 1) ? T2 : T3;
    int n = i >> 7, k = i & 127;
    T[n * 128 + k] = (unsigned short)bf16rne(W[k * 128 + n]);
  } else {
    if (tid < 16) {
      ((uint4*)(hbf + (size_t)NN * D))[tid] = make_uint4(0, 0, 0, 0);
      ((uint4*)(tbl2 + (size_t)NN * D))[tid] = make_uint4(0, 0, 0, 0);
    }
  }
}

// ---------------- CSR build, no global atomics ----------------
__global__ __launch_bounds__(1024) void hist_kernel(const int* __restrict__ src,
                                                    const int* __restrict__ dst,
                                                    int* __restrict__ partial_dst,
                                                    int* __restrict__ partial_src) {
  __shared__ int hd[NPR];
  __shared__ int hs[NPR];
  int tid = threadIdx.x;
  int c = blockIdx.x >> 3;
  int r = blockIdx.x & 7;
  int base = r * NPR;
  for (int i = tid; i < NPR; i += 1024) { hd[i] = 0; hs[i] = 0; }
  __syncthreads();
  int e0 = c * EPC;
  for (int i = tid; i < EPC; i += 1024) {
    int d = dst[e0 + i];
    int s = src[e0 + i];
    unsigned dr = (unsigned)(d - base);
    unsigned sr = (unsigned)(s - base);
    if (dr < NPR) atomicAdd(&hd[dr], 1);
    if (sr < NPR) atomicAdd(&hs[sr], 1);
  }
  __syncthreads();
  for (int i = tid; i < NPR; i += 1024) {
    partial_dst[c * NN + base + i] = hd[i];
    partial_src[c * NN + base + i] = hs[i];
  }
}

__device__ __forceinline__ int block_excl_scan(int v, int* wsum) {
  int lane = threadIdx.x & 63;
  int w = threadIdx.x >> 6;
  int incl = v;
#pragma unroll
  for (int off = 1; off < 64; off <<= 1) {
    int t = __shfl_up(incl, off);
    if (lane >= off) incl += t;
  }
  if (lane == 63) wsum[w] = incl;
  __syncthreads();
  int wo = 0;
#pragma unroll
  for (int j = 0; j < 4; ++j)
    if (j < w) wo += wsum[j];
  return wo + incl - v;
}

// fused reduce + scan phase 1 (padded degree, ceil16)
__global__ __launch_bounds__(256) void degscan_kernel(int* __restrict__ partial_dst,
                                                      const int* __restrict__ partial_src,
                                                      int* __restrict__ degtmp,
                                                      int* __restrict__ deg_out,
                                                      int* __restrict__ row_ptr,
                                                      int* __restrict__ partials, int N) {
  __shared__ int wsum[4];
  int d = blockIdx.x * 256 + threadIdx.x;
  int run = 0;
  if (d < N) {
#pragma unroll
    for (int c = 0; c < CH; ++c) {
      int v = partial_dst[c * NN + d];
      partial_dst[c * NN + d] = run;
      run += v;
    }
    degtmp[d] = run;
    int ro = 0;
#pragma unroll
    for (int c = 0; c < CH; ++c) ro += partial_src[c * NN + d];
    deg_out[d] = ro;
  }
  int pad = (run + 15) & ~15;
  int excl = block_excl_scan(pad, wsum);
  if (d < N) row_ptr[d] = excl;
  if (threadIdx.x == 255) partials[blockIdx.x] = excl + pad;
}

__global__ __launch_bounds__(256) void scan2(int* __restrict__ partials,
                                             int* __restrict__ row_ptr, int nb, int N) {
  __shared__ int wsum[4];
  int v = (threadIdx.x < nb) ? partials[threadIdx.x] : 0;
  int excl = block_excl_scan(v, wsum);
  if (threadIdx.x < nb) partials[threadIdx.x] = excl;
  if (threadIdx.x == nb - 1) row_ptr[N] = excl + v;
}

__global__ __launch_bounds__(256) void scan3(int* __restrict__ row_ptr,
                                             const int* __restrict__ partials, int N) {
  int i = blockIdx.x * 256 + threadIdx.x;
  if (i < N) row_ptr[i] += partials[blockIdx.x];
}

// fill + pad: LDS cursor scatter; chunk-0 blocks also write dummy-index tails.
__global__ __launch_bounds__(1024) void fill_kernel(const int* __restrict__ src,
                                                    const int* __restrict__ dst,
                                                    const int* __restrict__ row_ptr,
                                                    const int* __restrict__ partial_dst,
                                                    const int* __restrict__ degtmp,
                                                    int* __restrict__ csr_src) {
  __shared__ int cur[NPR];
  int tid = threadIdx.x;
  int c = blockIdx.x >> 3;
  int r = blockIdx.x & 7;
  int base = r * NPR;
  for (int i = tid; i < NPR; i += 1024)
    cur[i] = row_ptr[base + i] + partial_dst[c * NN + base + i];
  if (c == 0) {  // pad tails for this node range (disjoint from scatter targets)
    for (int i = tid; i < NPR; i += 1024) {
      int node = base + i;
      int s = row_ptr[node] + degtmp[node];
      int e = row_ptr[node + 1];
      for (int j = s; j < e; ++j) csr_src[j] = NN;
    }
  }
  __syncthreads();
  int e0 = c * EPC;
  for (int i = tid; i < EPC; i += 1024) {
    int d = dst[e0 + i];
    unsigned dr = (unsigned)(d - base);
    if (dr < NPR) {
      int pos = atomicAdd(&cur[dr], 1);
      csr_src[pos] = src[e0 + i];
    }
  }
}

// ---------------- fused agg + MFMA GEMM ----------------
// Block 256 = 4 waves; block covers 64 nodes; each wave owns 16 nodes.
// Phase 1 (per wave, per node): padded-CSR gather (quarter-wave per edge,
//   16 edges / 4KB in flight), f32 accumulate, normalize, pack bf16 into a
//   wave-private LDS patch (16 rows x 136-stride).
// Phase 2: A-fragments from own LDS patch, B-fragments from global WT
//   (L2-hot 32KB), 8 n-tiles x 4 k-chunks of mfma_f32_16x16x32_bf16.
// AMODE 0: sage (self+avg, /(deg+1)); AMODE 1: gcn (*rsqrt(max(deg,1))).
// GMODE 1: row scale rsqrt(max(deg_out,1)). OUT_BF: bf16 table else f32.
__device__ __forceinline__ void bacc(float* a, uint4 u) {
  a[0] += __uint_as_float(u.x << 16);
  a[1] += __uint_as_float(u.x & 0xffff0000u);
  a[2] += __uint_as_float(u.y << 16);
  a[3] += __uint_as_float(u.y & 0xffff0000u);
  a[4] += __uint_as_float(u.z << 16);
  a[5] += __uint_as_float(u.z & 0xffff0000u);
  a[6] += __uint_as_float(u.w << 16);
  a[7] += __uint_as_float(u.w & 0xffff0000u);
}

template <int AMODE, int GMODE, int OUT_BF>
__global__ __launch_bounds__(256, 4) void fused_kernel(
    const unsigned short* __restrict__ hb, const int* __restrict__ row_ptr,
    const int* __restrict__ csr_src, const int* __restrict__ degtmp,
    const int* __restrict__ deg_out, const unsigned short* __restrict__ WT,
    const float* __restrict__ bias, float* __restrict__ outf,
    unsigned short* __restrict__ outb, int N) {
  __shared__ unsigned short sA[4][16 * 136];  // per-wave patch, stride-136 pad
  int tid = threadIdx.x;
  int wv = tid >> 6;
  int lane = tid & 63;
  int q = lane >> 4;    // quarter
  int col = lane & 15;  // 16B granule within row
  int base = blockIdx.x * 64 + wv * 16;

  // ---- phase 1: aggregate 16 nodes ----
  for (int j = 0; j < 16; ++j) {
    int node = base + j;
    int cn = (node < N) ? node : N - 1;  // clamp; stores guarded later
    int start = row_ptr[cn];
    int iters = (row_ptr[cn + 1] - start) >> 4;
    float a0[8] = {0, 0, 0, 0, 0, 0, 0, 0};
    float a1[8] = {0, 0, 0, 0, 0, 0, 0, 0};
    float a2[8] = {0, 0, 0, 0, 0, 0, 0, 0};
    float a3[8] = {0, 0, 0, 0, 0, 0, 0, 0};
    const int* ce = csr_src + start + q;
    for (int it = 0; it < iters; ++it, ce += 16) {
      int i0 = ce[0];
      int i1 = ce[4];
      int i2 = ce[8];
      int i3 = ce[12];
      uint4 u0 = ((const uint4*)(hb + (size_t)i0 * D))[col];
      uint4 u1 = ((const uint4*)(hb + (size_t)i1 * D))[col];
      uint4 u2 = ((const uint4*)(hb + (size_t)i2 * D))[col];
      uint4 u3 = ((const uint4*)(hb + (size_t)i3 * D))[col];
      bacc(a0, u0);
      bacc(a1, u1);
      bacc(a2, u2);
      bacc(a3, u3);
    }
#pragma unroll
    for (int t = 0; t < 8; ++t) a0[t] = (a0[t] + a1[t]) + (a2[t] + a3[t]);
#pragma unroll
    for (int t = 0; t < 8; ++t) {
      a0[t] += __shfl_xor(a0[t], 16);
      a0[t] += __shfl_xor(a0[t], 32);
    }
    int indeg = degtmp[cn];
    if (AMODE == 0) {
      uint4 s = ((const uint4*)(hb + (size_t)cn * D))[col];
      float sf[8] = {0, 0, 0, 0, 0, 0, 0, 0};
      bacc(sf, s);
      float inv = 1.0f / (float)(indeg + 1);
#pragma unroll
      for (int t = 0; t < 8; ++t) a0[t] = (a0[t] + sf[t]) * inv;
    } else {
      float sc = rsqrtf(fmaxf((float)indeg, 1.0f));
#pragma unroll
      for (int t = 0; t < 8; ++t) a0[t] *= sc;
    }
    if (q == 0) {
      uint4 p;
      p.x = packbf(a0[0], a0[1]);
      p.y = packbf(a0[2], a0[3]);
      p.z = packbf(a0[4], a0[5]);
      p.w = packbf(a0[6], a0[7]);
      *(uint4*)&sA[wv][j * 136 + col * 8] = p;
    }
  }
  // same-wave LDS write->read: compiler inserts lgkmcnt wait; no barrier needed.

  // ---- phase 2: 16x128 MFMA tile from own patch ----
  int ln = col;  // A row / B col-within-tile
  bf16x8 af[4];
#pragma unroll
  for (int c = 0; c < 4; ++c)
    af[c] = *(const bf16x8*)&sA[wv][ln * 136 + c * 32 + q * 8];
  f32x4 acc[8];
#pragma unroll
  for (int t = 0; t < 8; ++t) acc[t] = (f32x4){0.f, 0.f, 0.f, 0.f};
#pragma unroll
  for (int t = 0; t < 8; ++t) {
    const unsigned short* Wr = WT + (size_t)(t * 16 + ln) * 128 + q * 8;
    bf16x8 b0 = *(const bf16x8*)(Wr + 0);
    bf16x8 b1 = *(const bf16x8*)(Wr + 32);
    bf16x8 b2 = *(const bf16x8*)(Wr + 64);
    bf16x8 b3 = *(const bf16x8*)(Wr + 96);
    acc[t] = __builtin_amdgcn_mfma_f32_16x16x32_bf16(af[0], b0, acc[t], 0, 0, 0);
    acc[t] = __builtin_amdgcn_mfma_f32_16x16x32_bf16(af[1], b1, acc[t], 0, 0, 0);
    acc[t] = __builtin_amdgcn_mfma_f32_16x16x32_bf16(af[2], b2, acc[t], 0, 0, 0);
    acc[t] = __builtin_amdgcn_mfma_f32_16x16x32_bf16(af[3], b3, acc[t], 0, 0, 0);
  }
  float scl[4];
#pragma unroll
  for (int r = 0; r < 4; ++r) {
    scl[r] = 1.0f;
    if (GMODE == 1) {
      int row = base + q * 4 + r;
      int rr = (row < N) ? row : 0;
      scl[r] = rsqrtf(fmaxf((float)deg_out[rr], 1.0f));
    }
  }
#pragma unroll
  for (int t = 0; t < 8; ++t) {
    float b = bias[t * 16 + ln];
#pragma unroll
    for (int r = 0; r < 4; ++r) {
      int row = base + q * 4 + r;
      if (row < N) {
        float v = (acc[t][r] + b) * scl[r];
        if (OUT_BF)
          outb[(size_t)row * 128 + t * 16 + ln] = (unsigned short)bf16rne(v);
        else
          outf[(size_t)row * 128 + t * 16 + ln] = v;
      }
    }
  }
}

// ---------------- launcher ----------------

extern "C" void kernel_launch(void* const* d_in, const int* in_sizes, int n_in,
                              void* d_out, int out_size, void* d_ws, size_t ws_size,
                              hipStream_t stream) {
  const float* x = (const float*)d_in[0];
  const float* W1 = (const float*)d_in[1];
  const float* b1 = (const float*)d_in[2];
  const float* W2 = (const float*)d_in[3];
  const float* b2 = (const float*)d_in[4];
  const float* W3 = (const float*)d_in[5];
  const float* b3 = (const float*)d_in[6];
  const int* src = (const int*)d_in[7];
  const int* dst = (const int*)d_in[8];
  float* out = (float*)d_out;

  const int N = NN;

  // workspace layout (~58 MB)
  unsigned short* hbf = (unsigned short*)d_ws;             // (NN+1)*D bf16
  unsigned short* tbl2 = hbf + (size_t)(NN + 1) * D;       // (NN+1)*D bf16
  unsigned short* WT1 = tbl2 + (size_t)(NN + 1) * D;       // 128*128 bf16
  unsigned short* WT2 = WT1 + D * D;
  unsigned short* WT3 = WT2 + D * D;
  int* partial_dst = (int*)(WT3 + D * D);                  // CH*NN
  int* partial_src = partial_dst + (size_t)CH * NN;        // CH*NN
  int* degtmp = partial_src + (size_t)CH * NN;             // NN
  int* deg_out = degtmp + NN;                              // NN
  int* row_ptr = deg_out + NN;                             // NN+1
  int* partials = row_ptr + NN + 1;                        // 256
  int* csr_src = partials + 256;                           // NE + 16*NN

  const int scanBlocks = (N + 255) / 256;  // 196

  cvtw_kernel<<<6443, 256, 0, stream>>>(x, W1, W2, W3, hbf, tbl2, WT1, WT2, WT3);
  hist_kernel<<<CH * RG, 1024, 0, stream>>>(src, dst, partial_dst, partial_src);
  degscan_kernel<<<scanBlocks, 256, 0, stream>>>(partial_dst, partial_src, degtmp,
                                                 deg_out, row_ptr, partials, N);
  scan2<<<1, 256, 0, stream>>>(partials, row_ptr, scanBlocks, N);
  scan3<<<scanBlocks, 256, 0, stream>>>(row_ptr, partials, N);
  fill_kernel<<<CH * RG, 1024, 0, stream>>>(src, dst, row_ptr, partial_dst, degtmp, csr_src);

  int fusedBlocks = (N + 63) / 64;  // 782

  // layer 1: sage(x)@W1+b1 -> tbl2
  fused_kernel<0, 0, 1><<<fusedBlocks, 256, 0, stream>>>(
      hbf, row_ptr, csr_src, degtmp, deg_out, WT1, b1, nullptr, tbl2, N);
  // layer 2: sage(h1)@W2+b2, fold norm_out -> hbf
  fused_kernel<0, 1, 1><<<fusedBlocks, 256, 0, stream>>>(
      tbl2, row_ptr, csr_src, degtmp, deg_out, WT2, b2, nullptr, hbf, N);
  // layer 3: gcn agg(h2)*norm_in @ W3 + b3 -> out (f32)
  fused_kernel<1, 0, 0><<<fusedBlocks, 256, 0, stream>>>(
      hbf, row_ptr, csr_src, degtmp, deg_out, WT3, b3, out, nullptr, N);
}

// Round 8
// 284.649 us; speedup vs baseline: 1.1135x; 1.1135x over previous
//
#include <hip/hip_runtime.h>

#define NN 50000
#define NE 800000
#define D 128

#define CH 64              // edge chunks
#define EPC (NE / CH)      // 12500 edges per chunk
#define RG 8               // node ranges
#define NPR (NN / RG)      // 6250 nodes per range

typedef short bf16x8 __attribute__((ext_vector_type(8)));
typedef float f32x4 __attribute__((ext_vector_type(4)));

// ---------------- bf16 helpers ----------------

__device__ __forceinline__ unsigned bf16rne(float f) {
  unsigned u = __float_as_uint(f);
  return (u + 0x7fffu + ((u >> 16) & 1u)) >> 16;
}
__device__ __forceinline__ unsigned packbf(float lo, float hi) {
  return bf16rne(lo) | (bf16rne(hi) << 16);
}

// fused: x->bf16 (blocks 0..6249), W^T bf16 x3 (blocks 6250..6441),
// zero row NN of BOTH gather tables (block 6442).
__global__ __launch_bounds__(256) void cvtw_kernel(const float* __restrict__ x,
                                                   const float* __restrict__ W1,
                                                   const float* __restrict__ W2,
                                                   const float* __restrict__ W3,
                                                   unsigned short* __restrict__ hbf,
                                                   unsigned short* __restrict__ tbl2,
                                                   unsigned short* __restrict__ T1,
                                                   unsigned short* __restrict__ T2,
                                                   unsigned short* __restrict__ T3) {
  int b = blockIdx.x;
  int tid = threadIdx.x;
  if (b < 6250) {
    int i = b * 256 + tid;  // NN*D/4 = 1.6M exactly
    float4 v = ((const float4*)x)[i];
    uint2 p;
    p.x = packbf(v.x, v.y);
    p.y = packbf(v.z, v.w);
    ((uint2*)hbf)[i] = p;
  } else if (b < 6442) {
    int g = b - 6250;
    int w = g >> 6;
    int i = (g & 63) * 256 + tid;  // 0..16383
    const float* W = (w == 0) ? W1 : (w == 1) ? W2 : W3;
    unsigned short* T = (w == 0) ? T1 : (w == 1) ? T2 : T3;
    int n = i >> 7, k = i & 127;
    T[n * 128 + k] = (unsigned short)bf16rne(W[k * 128 + n]);
  } else {
    if (tid < 16) {
      ((uint4*)(hbf + (size_t)NN * D))[tid] = make_uint4(0, 0, 0, 0);
      ((uint4*)(tbl2 + (size_t)NN * D))[tid] = make_uint4(0, 0, 0, 0);
    }
  }
}

// ---------------- CSR build, no global atomics ----------------
__global__ __launch_bounds__(1024) void hist_kernel(const int* __restrict__ src,
                                                    const int* __restrict__ dst,
                                                    int* __restrict__ partial_dst,
                                                    int* __restrict__ partial_src) {
  __shared__ int hd[NPR];
  __shared__ int hs[NPR];
  int tid = threadIdx.x;
  int c = blockIdx.x >> 3;
  int r = blockIdx.x & 7;
  int base = r * NPR;
  for (int i = tid; i < NPR; i += 1024) { hd[i] = 0; hs[i] = 0; }
  __syncthreads();
  int e0 = c * EPC;
  for (int i = tid; i < EPC; i += 1024) {
    int d = dst[e0 + i];
    int s = src[e0 + i];
    unsigned dr = (unsigned)(d - base);
    unsigned sr = (unsigned)(s - base);
    if (dr < NPR) atomicAdd(&hd[dr], 1);
    if (sr < NPR) atomicAdd(&hs[sr], 1);
  }
  __syncthreads();
  for (int i = tid; i < NPR; i += 1024) {
    partial_dst[c * NN + base + i] = hd[i];
    partial_src[c * NN + base + i] = hs[i];
  }
}

__device__ __forceinline__ int block_excl_scan(int v, int* wsum) {
  int lane = threadIdx.x & 63;
  int w = threadIdx.x >> 6;
  int incl = v;
#pragma unroll
  for (int off = 1; off < 64; off <<= 1) {
    int t = __shfl_up(incl, off);
    if (lane >= off) incl += t;
  }
  if (lane == 63) wsum[w] = incl;
  __syncthreads();
  int wo = 0;
#pragma unroll
  for (int j = 0; j < 4; ++j)
    if (j < w) wo += wsum[j];
  return wo + incl - v;
}

// fused reduce + scan phase 1 (padded degree, ceil16)
__global__ __launch_bounds__(256) void degscan_kernel(int* __restrict__ partial_dst,
                                                      const int* __restrict__ partial_src,
                                                      int* __restrict__ degtmp,
                                                      int* __restrict__ deg_out,
                                                      int* __restrict__ row_ptr,
                                                      int* __restrict__ partials, int N) {
  __shared__ int wsum[4];
  int d = blockIdx.x * 256 + threadIdx.x;
  int run = 0;
  if (d < N) {
#pragma unroll
    for (int c = 0; c < CH; ++c) {
      int v = partial_dst[c * NN + d];
      partial_dst[c * NN + d] = run;
      run += v;
    }
    degtmp[d] = run;
    int ro = 0;
#pragma unroll
    for (int c = 0; c < CH; ++c) ro += partial_src[c * NN + d];
    deg_out[d] = ro;
  }
  int pad = (run + 15) & ~15;
  int excl = block_excl_scan(pad, wsum);
  if (d < N) row_ptr[d] = excl;
  if (threadIdx.x == 255) partials[blockIdx.x] = excl + pad;
}

__global__ __launch_bounds__(256) void scan2(int* __restrict__ partials,
                                             int* __restrict__ row_ptr, int nb, int N) {
  __shared__ int wsum[4];
  int v = (threadIdx.x < nb) ? partials[threadIdx.x] : 0;
  int excl = block_excl_scan(v, wsum);
  if (threadIdx.x < nb) partials[threadIdx.x] = excl;
  if (threadIdx.x == nb - 1) row_ptr[N] = excl + v;
}

__global__ __launch_bounds__(256) void scan3(int* __restrict__ row_ptr,
                                             const int* __restrict__ partials, int N) {
  int i = blockIdx.x * 256 + threadIdx.x;
  if (i < N) row_ptr[i] += partials[blockIdx.x];
}

// fill + pad: LDS cursor scatter; chunk-0 blocks also write dummy-index tails.
__global__ __launch_bounds__(1024) void fill_kernel(const int* __restrict__ src,
                                                    const int* __restrict__ dst,
                                                    const int* __restrict__ row_ptr,
                                                    const int* __restrict__ partial_dst,
                                                    const int* __restrict__ degtmp,
                                                    int* __restrict__ csr_src) {
  __shared__ int cur[NPR];
  int tid = threadIdx.x;
  int c = blockIdx.x >> 3;
  int r = blockIdx.x & 7;
  int base = r * NPR;
  for (int i = tid; i < NPR; i += 1024)
    cur[i] = row_ptr[base + i] + partial_dst[c * NN + base + i];
  if (c == 0) {  // pad tails for this node range (disjoint from scatter targets)
    for (int i = tid; i < NPR; i += 1024) {
      int node = base + i;
      int s = row_ptr[node] + degtmp[node];
      int e = row_ptr[node + 1];
      for (int j = s; j < e; ++j) csr_src[j] = NN;
    }
  }
  __syncthreads();
  int e0 = c * EPC;
  for (int i = tid; i < EPC; i += 1024) {
    int d = dst[e0 + i];
    unsigned dr = (unsigned)(d - base);
    if (dr < NPR) {
      int pos = atomicAdd(&cur[dr], 1);
      csr_src[pos] = src[e0 + i];
    }
  }
}

// ---------------- fused agg + MFMA GEMM (4 nodes per wave) ----------------
// Block 256 = 4 waves; block covers 16 nodes (one MFMA row-tile); wave wv
// aggregates nodes base+wv*4 .. +3 (full-wave gather per node, quarter-wave
// per edge, 16 loads in flight), packs bf16 rows into the shared 16x136
// patch. One __syncthreads. Then the 16x128 output tile is split: wave wv
// computes n-tiles {2wv, 2wv+1} (8 MFMAs), B-fragments from L2-hot WT.
// Grid = N/16 = 3125 blocks = 12500 waves -> same gather TLP as unfused agg.
// AMODE 0: sage (self+avg, /(deg+1)); AMODE 1: gcn (*rsqrt(max(deg,1))).
// GMODE 1: row scale rsqrt(max(deg_out,1)). OUT_BF: bf16 table else f32.
__device__ __forceinline__ void bacc(float* a, uint4 u) {
  a[0] += __uint_as_float(u.x << 16);
  a[1] += __uint_as_float(u.x & 0xffff0000u);
  a[2] += __uint_as_float(u.y << 16);
  a[3] += __uint_as_float(u.y & 0xffff0000u);
  a[4] += __uint_as_float(u.z << 16);
  a[5] += __uint_as_float(u.z & 0xffff0000u);
  a[6] += __uint_as_float(u.w << 16);
  a[7] += __uint_as_float(u.w & 0xffff0000u);
}

template <int AMODE, int GMODE, int OUT_BF>
__global__ __launch_bounds__(256) void fused_kernel(
    const unsigned short* __restrict__ hb, const int* __restrict__ row_ptr,
    const int* __restrict__ csr_src, const int* __restrict__ degtmp,
    const int* __restrict__ deg_out, const unsigned short* __restrict__ WT,
    const float* __restrict__ bias, float* __restrict__ outf,
    unsigned short* __restrict__ outb, int N) {
  __shared__ unsigned short sA[16 * 136];  // 16-node patch, stride-136 pad
  int tid = threadIdx.x;
  int wv = tid >> 6;
  int lane = tid & 63;
  int q = lane >> 4;    // quarter
  int col = lane & 15;  // 16B granule within row
  int base = blockIdx.x * 16;  // N % 16 == 0: no tail

  // ---- phase 1: this wave aggregates 4 nodes ----
#pragma unroll
  for (int j = 0; j < 4; ++j) {
    int jt = wv * 4 + j;    // row in tile
    int node = base + jt;
    int start = row_ptr[node];
    int iters = (row_ptr[node + 1] - start) >> 4;
    float a0[8] = {0, 0, 0, 0, 0, 0, 0, 0};
    float a1[8] = {0, 0, 0, 0, 0, 0, 0, 0};
    float a2[8] = {0, 0, 0, 0, 0, 0, 0, 0};
    float a3[8] = {0, 0, 0, 0, 0, 0, 0, 0};
    const int* ce = csr_src + start + q;
    for (int it = 0; it < iters; ++it, ce += 16) {
      int i0 = ce[0];
      int i1 = ce[4];
      int i2 = ce[8];
      int i3 = ce[12];
      uint4 u0 = ((const uint4*)(hb + (size_t)i0 * D))[col];
      uint4 u1 = ((const uint4*)(hb + (size_t)i1 * D))[col];
      uint4 u2 = ((const uint4*)(hb + (size_t)i2 * D))[col];
      uint4 u3 = ((const uint4*)(hb + (size_t)i3 * D))[col];
      bacc(a0, u0);
      bacc(a1, u1);
      bacc(a2, u2);
      bacc(a3, u3);
    }
#pragma unroll
    for (int t = 0; t < 8; ++t) a0[t] = (a0[t] + a1[t]) + (a2[t] + a3[t]);
#pragma unroll
    for (int t = 0; t < 8; ++t) {
      a0[t] += __shfl_xor(a0[t], 16);
      a0[t] += __shfl_xor(a0[t], 32);
    }
    int indeg = degtmp[node];
    if (AMODE == 0) {
      uint4 s = ((const uint4*)(hb + (size_t)node * D))[col];
      float sf[8] = {0, 0, 0, 0, 0, 0, 0, 0};
      bacc(sf, s);
      float inv = 1.0f / (float)(indeg + 1);
#pragma unroll
      for (int t = 0; t < 8; ++t) a0[t] = (a0[t] + sf[t]) * inv;
    } else {
      float sc = rsqrtf(fmaxf((float)indeg, 1.0f));
#pragma unroll
      for (int t = 0; t < 8; ++t) a0[t] *= sc;
    }
    if (q == 0) {
      uint4 p;
      p.x = packbf(a0[0], a0[1]);
      p.y = packbf(a0[2], a0[3]);
      p.z = packbf(a0[4], a0[5]);
      p.w = packbf(a0[6], a0[7]);
      *(uint4*)&sA[jt * 136 + col * 8] = p;
    }
  }
  __syncthreads();

  // ---- phase 2: wave wv computes n-tiles 2wv, 2wv+1 of the 16x128 tile ----
  int ln = col;  // A row / B col-within-tile
  bf16x8 af[4];
#pragma unroll
  for (int c = 0; c < 4; ++c)
    af[c] = *(const bf16x8*)&sA[ln * 136 + c * 32 + q * 8];
  f32x4 acc[2];
#pragma unroll
  for (int t = 0; t < 2; ++t) acc[t] = (f32x4){0.f, 0.f, 0.f, 0.f};
#pragma unroll
  for (int t = 0; t < 2; ++t) {
    int nt = wv * 2 + t;
    const unsigned short* Wr = WT + (size_t)(nt * 16 + ln) * 128 + q * 8;
    bf16x8 b0 = *(const bf16x8*)(Wr + 0);
    bf16x8 b1 = *(const bf16x8*)(Wr + 32);
    bf16x8 b2 = *(const bf16x8*)(Wr + 64);
    bf16x8 b3 = *(const bf16x8*)(Wr + 96);
    acc[t] = __builtin_amdgcn_mfma_f32_16x16x32_bf16(af[0], b0, acc[t], 0, 0, 0);
    acc[t] = __builtin_amdgcn_mfma_f32_16x16x32_bf16(af[1], b1, acc[t], 0, 0, 0);
    acc[t] = __builtin_amdgcn_mfma_f32_16x16x32_bf16(af[2], b2, acc[t], 0, 0, 0);
    acc[t] = __builtin_amdgcn_mfma_f32_16x16x32_bf16(af[3], b3, acc[t], 0, 0, 0);
  }
  float scl[4];
#pragma unroll
  for (int r = 0; r < 4; ++r) {
    scl[r] = 1.0f;
    if (GMODE == 1) scl[r] = rsqrtf(fmaxf((float)deg_out[base + q * 4 + r], 1.0f));
  }
#pragma unroll
  for (int t = 0; t < 2; ++t) {
    int nt = wv * 2 + t;
    float b = bias[nt * 16 + ln];
#pragma unroll
    for (int r = 0; r < 4; ++r) {
      int row = base + q * 4 + r;  // always < N (N % 16 == 0)
      float v = (acc[t][r] + b) * scl[r];
      if (OUT_BF)
        outb[(size_t)row * 128 + nt * 16 + ln] = (unsigned short)bf16rne(v);
      else
        outf[(size_t)row * 128 + nt * 16 + ln] = v;
    }
  }
}

// ---------------- launcher ----------------

extern "C" void kernel_launch(void* const* d_in, const int* in_sizes, int n_in,
                              void* d_out, int out_size, void* d_ws, size_t ws_size,
                              hipStream_t stream) {
  const float* x = (const float*)d_in[0];
  const float* W1 = (const float*)d_in[1];
  const float* b1 = (const float*)d_in[2];
  const float* W2 = (const float*)d_in[3];
  const float* b2 = (const float*)d_in[4];
  const float* W3 = (const float*)d_in[5];
  const float* b3 = (const float*)d_in[6];
  const int* src = (const int*)d_in[7];
  const int* dst = (const int*)d_in[8];
  float* out = (float*)d_out;

  const int N = NN;

  // workspace layout (~58 MB)
  unsigned short* hbf = (unsigned short*)d_ws;             // (NN+1)*D bf16
  unsigned short* tbl2 = hbf + (size_t)(NN + 1) * D;       // (NN+1)*D bf16
  unsigned short* WT1 = tbl2 + (size_t)(NN + 1) * D;       // 128*128 bf16
  unsigned short* WT2 = WT1 + D * D;
  unsigned short* WT3 = WT2 + D * D;
  int* partial_dst = (int*)(WT3 + D * D);                  // CH*NN
  int* partial_src = partial_dst + (size_t)CH * NN;        // CH*NN
  int* degtmp = partial_src + (size_t)CH * NN;             // NN
  int* deg_out = degtmp + NN;                              // NN
  int* row_ptr = deg_out + NN;                             // NN+1
  int* partials = row_ptr + NN + 1;                        // 256
  int* csr_src = partials + 256;                           // NE + 16*NN

  const int scanBlocks = (N + 255) / 256;  // 196

  cvtw_kernel<<<6443, 256, 0, stream>>>(x, W1, W2, W3, hbf, tbl2, WT1, WT2, WT3);
  hist_kernel<<<CH * RG, 1024, 0, stream>>>(src, dst, partial_dst, partial_src);
  degscan_kernel<<<scanBlocks, 256, 0, stream>>>(partial_dst, partial_src, degtmp,
                                                 deg_out, row_ptr, partials, N);
  scan2<<<1, 256, 0, stream>>>(partials, row_ptr, scanBlocks, N);
  scan3<<<scanBlocks, 256, 0, stream>>>(row_ptr, partials, N);
  fill_kernel<<<CH * RG, 1024, 0, stream>>>(src, dst, row_ptr, partial_dst, degtmp, csr_src);

  int fusedBlocks = N / 16;  // 3125 (N % 16 == 0)

  // layer 1: sage(x)@W1+b1 -> tbl2
  fused_kernel<0, 0, 1><<<fusedBlocks, 256, 0, stream>>>(
      hbf, row_ptr, csr_src, degtmp, deg_out, WT1, b1, nullptr, tbl2, N);
  // layer 2: sage(h1)@W2+b2, fold norm_out -> hbf
  fused_kernel<0, 1, 1><<<fusedBlocks, 256, 0, stream>>>(
      tbl2, row_ptr, csr_src, degtmp, deg_out, WT2, b2, nullptr, hbf, N);
  // layer 3: gcn agg(h2)*norm_in @ W3 + b3 -> out (f32)
  fused_kernel<1, 0, 0><<<fusedBlocks, 256, 0, stream>>>(
      hbf, row_ptr, csr_src, degtmp, deg_out, WT3, b3, out, nullptr, N);
}